// Round 1
// baseline (742.803 us; speedup 1.0000x reference)
//
#include <hip/hip_runtime.h>
#include <math.h>

namespace {
constexpr int Bb  = 8;
constexpr int Dd  = 384;
constexpr int HIN = 128;
constexpr int Cc  = 96;
constexpr int Nn  = 1024;
constexpr int NH  = 4;
constexpr int HD  = 24;
}
#define BN_EPS 1e-5f
#define QSCALE 0.20412414523193154f  /* 24^-0.5 */

__device__ __forceinline__ float bn_relu6(float y, const float* __restrict__ bn, int c) {
    float gam = bn[c], bet = bn[Cc + c], mu = bn[2*Cc + c], var = bn[3*Cc + c];
    float s = gam / sqrtf(var + BN_EPS);
    float r = (y - mu) * s + bet;
    return fminf(fmaxf(r, 0.0f), 6.0f);
}

// ---------------------------------------------------------------------------
// Stem: fused (grouped 4x4/s4 conv | 4x4 maxpool+grouped1x1 | 4x4 avgpool+grouped1x1)
// Each output (b,g,oh,ow) consumes the same 64 input floats for all 3 branches.
// Outputs in [B][C][N] layout (coalesced writes).
// ---------------------------------------------------------------------------
__global__ __launch_bounds__(256) void stem_kernel(
    const float* __restrict__ x, const float* __restrict__ w_le,
    const float* __restrict__ b_le, const float* __restrict__ bn_le,
    const float* __restrict__ w_max, const float* __restrict__ b_max, const float* __restrict__ bn_max,
    const float* __restrict__ w_avg, const float* __restrict__ b_avg, const float* __restrict__ bn_avg,
    float* __restrict__ xq, float* __restrict__ tmx, float* __restrict__ tav)
{
    const int tid = threadIdx.x;
    const int n = blockIdx.x * 256 + tid;
    const int g = blockIdx.y;
    const int b = blockIdx.z;
    const int oh = n >> 5, ow = n & 31;

    const float* xb = x + (((size_t)b * Dd + 4*g) * HIN + 4*oh) * HIN + 4*ow;
    float conv = 0.0f, mxv = 0.0f, avv = 0.0f;
    #pragma unroll
    for (int i = 0; i < 4; ++i) {
        float cmax = -3.0e38f, csum = 0.0f;
        #pragma unroll
        for (int kh = 0; kh < 4; ++kh) {
            const float4 v = *(const float4*)(xb + ((size_t)i * HIN + kh) * HIN);
            const float* wl = w_le + (((g*4 + i)*4 + kh) * 4);
            conv = fmaf(v.x, wl[0], conv);
            conv = fmaf(v.y, wl[1], conv);
            conv = fmaf(v.z, wl[2], conv);
            conv = fmaf(v.w, wl[3], conv);
            cmax = fmaxf(cmax, fmaxf(fmaxf(v.x, v.y), fmaxf(v.z, v.w)));
            csum += (v.x + v.y) + (v.z + v.w);
        }
        mxv = fmaf(cmax, w_max[g*4 + i], mxv);
        avv = fmaf(csum * (1.0f/16.0f), w_avg[g*4 + i], avv);
    }
    const float xqv = bn_relu6(conv + b_le[g], bn_le, g);
    const float tm  = bn_relu6(mxv  + b_max[g], bn_max, g);
    const float ta  = bn_relu6(avv  + b_avg[g], bn_avg, g);
    const size_t o = ((size_t)b * Cc + g) * Nn + n;
    xq[o] = xqv; tmx[o] = tm; tav[o] = ta;
}

// ---------------------------------------------------------------------------
// Projections: q = xq@w_q * scale; (k1,v1)=tmx@w_kv; (k2,v2)=tav@w_kv.
// Outputs laid out [B][nH][N][24] for contiguous attention tile loads.
// ---------------------------------------------------------------------------
__global__ __launch_bounds__(256) void proj_kernel(
    const float* __restrict__ xq, const float* __restrict__ tmx, const float* __restrict__ tav,
    const float* __restrict__ w_q, const float* __restrict__ w_kv,
    float* __restrict__ qp, float* __restrict__ k1, float* __restrict__ v1,
    float* __restrict__ k2, float* __restrict__ v2)
{
    const int tid = threadIdx.x;
    const int n0 = blockIdx.x * 32;
    const int b  = blockIdx.y;
    __shared__ float axq[32*101];
    __shared__ float amx[32*101];
    __shared__ float aav[32*101];
    __shared__ float lw[96*97];

    for (int e = tid; e < 96*32; e += 256) {
        const int c = e >> 5, j = e & 31;
        const size_t src = ((size_t)b * Cc + c) * Nn + n0 + j;
        axq[j*101 + c] = xq[src];
        amx[j*101 + c] = tmx[src];
        aav[j*101 + c] = tav[src];
    }

    const int tn = (tid & 7) * 4;   // 4 rows (n)
    const int tc = (tid >> 3) * 3;  // 3 cols

    // ---- phase A: q ----
    __syncthreads();
    for (int e = tid; e < 96*96; e += 256) lw[(e/96)*97 + (e%96)] = w_q[e];
    __syncthreads();
    {
        float acc[4][3] = {};
        for (int k = 0; k < 96; ++k) {
            const float w0 = lw[k*97 + tc + 0];
            const float w1 = lw[k*97 + tc + 1];
            const float w2 = lw[k*97 + tc + 2];
            #pragma unroll
            for (int i = 0; i < 4; ++i) {
                const float a = axq[(tn+i)*101 + k];
                acc[i][0] = fmaf(a, w0, acc[i][0]);
                acc[i][1] = fmaf(a, w1, acc[i][1]);
                acc[i][2] = fmaf(a, w2, acc[i][2]);
            }
        }
        #pragma unroll
        for (int j = 0; j < 3; ++j) {
            const int col = tc + j, h = col / HD, d = col - h*HD;
            #pragma unroll
            for (int i = 0; i < 4; ++i)
                qp[(((size_t)b*NH + h)*Nn + n0 + tn + i)*HD + d] = acc[i][j] * QSCALE;
        }
    }

    // ---- phase B: k halves ----
    __syncthreads();
    for (int e = tid; e < 96*96; e += 256) lw[(e/96)*97 + (e%96)] = w_kv[(e/96)*192 + (e%96)];
    __syncthreads();
    {
        float a1c[4][3] = {}, a2c[4][3] = {};
        for (int k = 0; k < 96; ++k) {
            const float w0 = lw[k*97 + tc + 0];
            const float w1 = lw[k*97 + tc + 1];
            const float w2 = lw[k*97 + tc + 2];
            #pragma unroll
            for (int i = 0; i < 4; ++i) {
                const float a1 = amx[(tn+i)*101 + k];
                const float a2 = aav[(tn+i)*101 + k];
                a1c[i][0] = fmaf(a1, w0, a1c[i][0]);
                a1c[i][1] = fmaf(a1, w1, a1c[i][1]);
                a1c[i][2] = fmaf(a1, w2, a1c[i][2]);
                a2c[i][0] = fmaf(a2, w0, a2c[i][0]);
                a2c[i][1] = fmaf(a2, w1, a2c[i][1]);
                a2c[i][2] = fmaf(a2, w2, a2c[i][2]);
            }
        }
        #pragma unroll
        for (int j = 0; j < 3; ++j) {
            const int col = tc + j, h = col / HD, d = col - h*HD;
            #pragma unroll
            for (int i = 0; i < 4; ++i) {
                const size_t dst = (((size_t)b*NH + h)*Nn + n0 + tn + i)*HD + d;
                k1[dst] = a1c[i][j];
                k2[dst] = a2c[i][j];
            }
        }
    }

    // ---- phase C: v halves ----
    __syncthreads();
    for (int e = tid; e < 96*96; e += 256) lw[(e/96)*97 + (e%96)] = w_kv[(e/96)*192 + 96 + (e%96)];
    __syncthreads();
    {
        float a1c[4][3] = {}, a2c[4][3] = {};
        for (int k = 0; k < 96; ++k) {
            const float w0 = lw[k*97 + tc + 0];
            const float w1 = lw[k*97 + tc + 1];
            const float w2 = lw[k*97 + tc + 2];
            #pragma unroll
            for (int i = 0; i < 4; ++i) {
                const float a1 = amx[(tn+i)*101 + k];
                const float a2 = aav[(tn+i)*101 + k];
                a1c[i][0] = fmaf(a1, w0, a1c[i][0]);
                a1c[i][1] = fmaf(a1, w1, a1c[i][1]);
                a1c[i][2] = fmaf(a1, w2, a1c[i][2]);
                a2c[i][0] = fmaf(a2, w0, a2c[i][0]);
                a2c[i][1] = fmaf(a2, w1, a2c[i][1]);
                a2c[i][2] = fmaf(a2, w2, a2c[i][2]);
            }
        }
        #pragma unroll
        for (int j = 0; j < 3; ++j) {
            const int col = tc + j, h = col / HD, d = col - h*HD;
            #pragma unroll
            for (int i = 0; i < 4; ++i) {
                const size_t dst = (((size_t)b*NH + h)*Nn + n0 + tn + i)*HD + d;
                v1[dst] = a1c[i][j];
                v2[dst] = a2c[i][j];
            }
        }
    }
}

// ---------------------------------------------------------------------------
// Attention: both branches, online softmax. 1 query/thread, 4-way m-split
// across lanes (tid&3); shuffle merge at end. Per-split tile stride 392
// (392 % 32 == 8) so the quad-broadcast b128 reads are conflict-free.
// ---------------------------------------------------------------------------
__global__ __launch_bounds__(256) void attn_kernel(
    const float* __restrict__ qp, const float* __restrict__ k1, const float* __restrict__ v1,
    const float* __restrict__ k2, const float* __restrict__ v2,
    const float* __restrict__ bias_table, float* __restrict__ osum)
{
    const int tid = threadIdx.x;
    const int h = blockIdx.y, b = blockIdx.z;
    const int split = tid & 3;
    const int ql = tid >> 2;                 // 0..63
    const int n = blockIdx.x * 64 + ql;

    __shared__ float biasl[3969];
    __shared__ float k1t[4*392];
    __shared__ float k2t[4*392];
    __shared__ float v1t[4*392];
    __shared__ float v2t[4*392];

    for (int e = tid; e < 3969; e += 256) biasl[e] = bias_table[e*NH + h];

    const size_t kvbase = ((size_t)b*NH + h) * (size_t)Nn * HD;
    const float* qrow = qp + kvbase + (size_t)n * HD;
    float qreg[HD];
    #pragma unroll
    for (int d4 = 0; d4 < 6; ++d4) {
        const float4 v = *(const float4*)(qrow + 4*d4);
        qreg[4*d4+0] = v.x; qreg[4*d4+1] = v.y; qreg[4*d4+2] = v.z; qreg[4*d4+3] = v.w;
    }

    float o1[HD], o2[HD];
    #pragma unroll
    for (int d = 0; d < HD; ++d) { o1[d] = 0.0f; o2[d] = 0.0f; }
    float m1 = -3.0e38f, m2 = -3.0e38f, l1 = 0.0f, l2 = 0.0f;
    const int yn = n >> 5, xn = n & 31;

    for (int it = 0; it < 16; ++it) {
        __syncthreads();
        for (int e = tid; e < 4*384; e += 256) {
            const int s = e / 384, r = e - s*384;
            const size_t src = kvbase + (size_t)s*(256*HD) + (size_t)it*(16*HD) + r;
            const int dst = s*392 + r;
            k1t[dst] = k1[src];
            k2t[dst] = k2[src];
            v1t[dst] = v1[src];
            v2t[dst] = v2[src];
        }
        __syncthreads();

        const float* kk1 = k1t + split*392;
        const float* kk2 = k2t + split*392;
        const float* vv1 = v1t + split*392;
        const float* vv2 = v2t + split*392;
        const int mbase = split*256 + it*16;

        float s1[16], s2[16];
        float t1 = -3.0e38f, t2 = -3.0e38f;
        #pragma unroll
        for (int mi = 0; mi < 16; ++mi) {
            const int m = mbase + mi;
            const int ym = m >> 5, xm = m & 31;
            const float bv = biasl[(yn - ym + 31)*63 + (xn - xm + 31)];
            float d1 = bv, d2 = bv;
            #pragma unroll
            for (int d = 0; d < HD; ++d) {
                d1 = fmaf(qreg[d], kk1[mi*HD + d], d1);
                d2 = fmaf(qreg[d], kk2[mi*HD + d], d2);
            }
            s1[mi] = d1; s2[mi] = d2;
            t1 = fmaxf(t1, d1); t2 = fmaxf(t2, d2);
        }
        {   // branch 1 online update
            const float M = fmaxf(m1, t1);
            const float c = __expf(m1 - M);
            l1 *= c;
            #pragma unroll
            for (int d = 0; d < HD; ++d) o1[d] *= c;
            #pragma unroll
            for (int mi = 0; mi < 16; ++mi) {
                const float p = __expf(s1[mi] - M);
                l1 += p;
                const float* vr = vv1 + mi*HD;
                #pragma unroll
                for (int d = 0; d < HD; ++d) o1[d] = fmaf(p, vr[d], o1[d]);
            }
            m1 = M;
        }
        {   // branch 2 online update
            const float M = fmaxf(m2, t2);
            const float c = __expf(m2 - M);
            l2 *= c;
            #pragma unroll
            for (int d = 0; d < HD; ++d) o2[d] *= c;
            #pragma unroll
            for (int mi = 0; mi < 16; ++mi) {
                const float p = __expf(s2[mi] - M);
                l2 += p;
                const float* vr = vv2 + mi*HD;
                #pragma unroll
                for (int d = 0; d < HD; ++d) o2[d] = fmaf(p, vr[d], o2[d]);
            }
            m2 = M;
        }
    }

    {   // merge branch 1 across the 4 m-splits (lanes xor 1,2)
        float M = m1;
        M = fmaxf(M, __shfl_xor(M, 1));
        M = fmaxf(M, __shfl_xor(M, 2));
        const float c = __expf(m1 - M);
        l1 *= c;
        #pragma unroll
        for (int d = 0; d < HD; ++d) o1[d] *= c;
        l1 += __shfl_xor(l1, 1);
        l1 += __shfl_xor(l1, 2);
        #pragma unroll
        for (int d = 0; d < HD; ++d) {
            o1[d] += __shfl_xor(o1[d], 1);
            o1[d] += __shfl_xor(o1[d], 2);
        }
    }
    {   // merge branch 2
        float M = m2;
        M = fmaxf(M, __shfl_xor(M, 1));
        M = fmaxf(M, __shfl_xor(M, 2));
        const float c = __expf(m2 - M);
        l2 *= c;
        #pragma unroll
        for (int d = 0; d < HD; ++d) o2[d] *= c;
        l2 += __shfl_xor(l2, 1);
        l2 += __shfl_xor(l2, 2);
        #pragma unroll
        for (int d = 0; d < HD; ++d) {
            o2[d] += __shfl_xor(o2[d], 1);
            o2[d] += __shfl_xor(o2[d], 2);
        }
    }

    if (split == 0) {
        const float i1 = 1.0f / l1, i2 = 1.0f / l2;
        float* orow = osum + ((size_t)b*Nn + n)*Cc + h*HD;
        #pragma unroll
        for (int d4 = 0; d4 < 6; ++d4) {
            float4 v;
            v.x = o1[4*d4+0]*i1 + o2[4*d4+0]*i2;
            v.y = o1[4*d4+1]*i1 + o2[4*d4+1]*i2;
            v.z = o1[4*d4+2]*i1 + o2[4*d4+2]*i2;
            v.w = o1[4*d4+3]*i1 + o2[4*d4+3]*i2;
            *(float4*)(orow + 4*d4) = v;
        }
    }
}

// ---------------------------------------------------------------------------
// w_fused[c][o] = sum_c2 w_proj[c][c2] * w_out[o][c2];
// b_fused[o]   = b_out[o] + 2 * sum_c b_proj[c] * w_out[o][c]
// ---------------------------------------------------------------------------
__global__ __launch_bounds__(256) void fusew_kernel(
    const float* __restrict__ w_proj, const float* __restrict__ b_proj,
    const float* __restrict__ w_out, const float* __restrict__ b_out,
    float* __restrict__ wf, float* __restrict__ bf)
{
    const int e = blockIdx.x * 256 + threadIdx.x;
    if (e < Cc * Dd) {
        const int c = e / Dd, o = e - c*Dd;
        const float* wp = w_proj + c*Cc;
        const float* wo = w_out + (size_t)o*Cc;
        float acc = 0.0f;
        for (int c2 = 0; c2 < Cc; ++c2) acc = fmaf(wp[c2], wo[c2], acc);
        wf[e] = acc;
    }
    if (e < Dd) {
        const float* wo = w_out + (size_t)e*Cc;
        float acc = 0.0f;
        for (int c = 0; c < Cc; ++c) acc = fmaf(b_proj[c], wo[c], acc);
        bf[e] = b_out[e] + 2.0f * acc;
    }
}

// ---------------------------------------------------------------------------
// out_small[b][o][n] = osum[b][n][:] . wf[:][o] + bf[o]
// ---------------------------------------------------------------------------
__global__ __launch_bounds__(256) void outgemm_kernel(
    const float* __restrict__ osum, const float* __restrict__ wf, const float* __restrict__ bf,
    float* __restrict__ outs)
{
    const int tid = threadIdx.x;
    const int n0 = blockIdx.x * 32;
    const int b  = blockIdx.y;
    __shared__ float ax[32*101];
    __shared__ float lw[96*132];
    for (int e = tid; e < 32*96; e += 256) {
        const int n = e / 96, c = e - n*96;
        ax[n*101 + c] = osum[((size_t)b*Nn + n0 + n)*Cc + c];
    }
    const int tn = (tid & 7) * 4;
    const int tj = (tid >> 3) * 4;
    for (int o0 = 0; o0 < Dd; o0 += 128) {
        __syncthreads();
        for (int e = tid; e < 96*128; e += 256) {
            const int c = e >> 7, j = e & 127;
            lw[c*132 + j] = wf[(size_t)c*Dd + o0 + j];
        }
        __syncthreads();
        float acc[4][4] = {};
        for (int c = 0; c < 96; ++c) {
            const float4 wv = *(const float4*)&lw[c*132 + tj];
            #pragma unroll
            for (int i = 0; i < 4; ++i) {
                const float a = ax[(tn+i)*101 + c];
                acc[i][0] = fmaf(a, wv.x, acc[i][0]);
                acc[i][1] = fmaf(a, wv.y, acc[i][1]);
                acc[i][2] = fmaf(a, wv.z, acc[i][2]);
                acc[i][3] = fmaf(a, wv.w, acc[i][3]);
            }
        }
        #pragma unroll
        for (int j = 0; j < 4; ++j) {
            const int o = o0 + tj + j;
            const float bb = bf[o];
            #pragma unroll
            for (int i = 0; i < 4; ++i)
                outs[((size_t)b*Dd + o)*Nn + n0 + tn + i] = acc[i][j] + bb;
        }
    }
}

// ---------------------------------------------------------------------------
// Bilinear x4 upsample, align_corners=True: 32x32 -> 128x128 per (b,ch).
// ---------------------------------------------------------------------------
__global__ __launch_bounds__(256) void upsample_kernel(
    const float* __restrict__ src, float* __restrict__ dst)
{
    const int gid = blockIdx.x * 256 + threadIdx.x;   // 12,582,912 total
    const int ox4 = gid & 31;
    const int oy  = (gid >> 5) & 127;
    const int bc  = gid >> 12;                         // b*384 + ch
    const float* s = src + (size_t)bc * 1024;
    const float sy = oy * (31.0f / 127.0f);
    const int y0 = (int)sy;
    const int y1 = min(y0 + 1, 31);
    const float wy = sy - (float)y0;
    const float* r0 = s + y0 * 32;
    const float* r1 = s + y1 * 32;
    float res[4];
    #pragma unroll
    for (int j = 0; j < 4; ++j) {
        const int ox = ox4 * 4 + j;
        const float sx = ox * (31.0f / 127.0f);
        const int x0 = (int)sx;
        const int x1 = min(x0 + 1, 31);
        const float wx = sx - (float)x0;
        const float t0 = r0[x0] * (1.0f - wx) + r0[x1] * wx;
        const float t1 = r1[x0] * (1.0f - wx) + r1[x1] * wx;
        res[j] = t0 * (1.0f - wy) + t1 * wy;
    }
    *(float4*)(dst + (size_t)gid * 4) = make_float4(res[0], res[1], res[2], res[3]);
}

// ---------------------------------------------------------------------------
extern "C" void kernel_launch(void* const* d_in, const int* in_sizes, int n_in,
                              void* d_out, int out_size, void* d_ws, size_t ws_size,
                              hipStream_t stream)
{
    const float* x      = (const float*)d_in[0];
    const float* w_le   = (const float*)d_in[1];
    const float* b_le   = (const float*)d_in[2];
    const float* bn_le  = (const float*)d_in[3];
    const float* w_max  = (const float*)d_in[4];
    const float* b_max  = (const float*)d_in[5];
    const float* bn_max = (const float*)d_in[6];
    const float* w_avg  = (const float*)d_in[7];
    const float* b_avg  = (const float*)d_in[8];
    const float* bn_avg = (const float*)d_in[9];
    const float* btab   = (const float*)d_in[10];
    const float* w_q    = (const float*)d_in[11];
    const float* w_kv   = (const float*)d_in[12];
    const float* w_proj = (const float*)d_in[13];
    const float* b_proj = (const float*)d_in[14];
    const float* w_out  = (const float*)d_in[15];
    const float* b_out  = (const float*)d_in[16];
    (void)in_sizes; (void)n_in; (void)out_size; (void)ws_size;

    float* ws = (float*)d_ws;
    const size_t T = (size_t)Bb * Cc * Nn;   // 786432
    float* xq   = ws + 0*T;
    float* tmx  = ws + 1*T;
    float* tav  = ws + 2*T;
    float* qp   = ws + 3*T;
    float* outs = ws;            // aliases [xq..qp) — safe: written after attention
    float* k1   = ws + 4*T;
    float* v1   = ws + 5*T;
    float* k2   = ws + 6*T;
    float* v2   = ws + 7*T;
    float* osum = ws + 8*T;
    float* wf   = ws + 9*T;            // 96*384
    float* bf   = ws + 9*T + 96*384;   // 384

    stem_kernel<<<dim3(4, 96, 8), 256, 0, stream>>>(
        x, w_le, b_le, bn_le, w_max, b_max, bn_max, w_avg, b_avg, bn_avg, xq, tmx, tav);
    proj_kernel<<<dim3(32, 8), 256, 0, stream>>>(
        xq, tmx, tav, w_q, w_kv, qp, k1, v1, k2, v2);
    fusew_kernel<<<dim3(144), 256, 0, stream>>>(w_proj, b_proj, w_out, b_out, wf, bf);
    attn_kernel<<<dim3(16, 4, 8), 256, 0, stream>>>(qp, k1, v1, k2, v2, btab, osum);
    outgemm_kernel<<<dim3(32, 8), 256, 0, stream>>>(osum, wf, bf, outs);
    upsample_kernel<<<dim3(49152), 256, 0, stream>>>(outs, (float*)d_out);
}